// Round 2
// baseline (353.185 us; speedup 1.0000x reference)
//
#include <hip/hip_runtime.h>

#define DF 256
#define HID 16
#define NXCD 8

__device__ __forceinline__ int xcc_id() {
    unsigned x;
    asm volatile("s_getreg_b32 %0, hwreg(HW_REG_XCC_ID)" : "=s"(x));
    return (int)(x & 7);
}

// Tiny precompute: w[k] = sum_j W[k,j] * W_fc[j];  c = b_conv . W_fc + b_fc
__global__ void prep_kernel(const float* __restrict__ W, const float* __restrict__ b_conv,
                            const float* __restrict__ W_fc, const float* __restrict__ b_fc,
                            float* __restrict__ wvec, float* __restrict__ cterm) {
    int k = threadIdx.x;  // 256 threads
    float acc = 0.f;
#pragma unroll
    for (int j = 0; j < HID; ++j) acc += W[k * HID + j] * W_fc[j];
    wvec[k] = acc;
    if (k == 0) {
        float c = 0.f;
#pragma unroll
        for (int j = 0; j < HID; ++j) c += b_conv[j] * W_fc[j];
        cterm[0] = c + b_fc[0];
    }
}

// Degree count as float adds of 1.0 (exact). MULTI: per-XCD copy, L2-local atomic.
template<bool MULTI>
__global__ void count_kernel(const int* __restrict__ dst, float* __restrict__ buf, int N, int E) {
    const size_t base = MULTI ? (size_t)xcc_id() * N : 0;
    int stride = gridDim.x * blockDim.x;
    for (int e = blockIdx.x * blockDim.x + threadIdx.x; e < E; e += stride) {
        if (MULTI)
            __hip_atomic_fetch_add(&buf[base + (size_t)dst[e]], 1.0f,
                                   __ATOMIC_RELAXED, __HIP_MEMORY_SCOPE_WORKGROUP);
        else
            atomicAdd(&buf[dst[e]], 1.0f);
    }
}

// Per-node: s = x[row].w (wave dot), deg = 1 + sum_k buf[k][row],
// t[row] = dinv*s, out init = s/deg + c (self-loop + fused bias)
template<int NC>
__global__ void node_kernel(const float* __restrict__ x, const float* __restrict__ buf,
                            const float* __restrict__ wvec, const float* __restrict__ cterm,
                            float* __restrict__ dinv, float* __restrict__ tval,
                            float* __restrict__ out, int N) {
    int lane = threadIdx.x & 63;
    int row = blockIdx.x * 4 + (threadIdx.x >> 6);
    if (row >= N) return;
    float4 wv = reinterpret_cast<const float4*>(wvec)[lane];
    float4 xv = reinterpret_cast<const float4*>(x + (size_t)row * DF)[lane];
    float acc = xv.x * wv.x + xv.y * wv.y + xv.z * wv.z + xv.w * wv.w;
#pragma unroll
    for (int off = 32; off > 0; off >>= 1) acc += __shfl_xor(acc, off, 64);
    // deg contributions: lanes 0..NC-1 read one copy each, reduce over 8-lane group
    float d = (lane < NC) ? buf[(size_t)lane * N + row] : 0.f;
    if (NC > 1) {
#pragma unroll
        for (int off = 4; off > 0; off >>= 1) d += __shfl_xor(d, off, 64);
    }
    if (lane == 0) {
        float deg = 1.0f + d;
        float di = rsqrtf(deg);
        dinv[row] = di;
        tval[row] = acc * di;
        out[row] = acc / deg + cterm[0];
    }
}

// Edge scatter: buf[xcd][dst] += t[src]  (L2-local atomics; t is 400KB, cache-resident)
template<bool MULTI>
__global__ void scatter_kernel(const int* __restrict__ src, const int* __restrict__ dst,
                               const float* __restrict__ tval, float* __restrict__ buf,
                               int N, int E) {
    const size_t base = MULTI ? (size_t)xcc_id() * N : 0;
    int stride = gridDim.x * blockDim.x;
    for (int e = blockIdx.x * blockDim.x + threadIdx.x; e < E; e += stride) {
        int si = src[e];
        int di = dst[e];
        float v = tval[si];
        if (MULTI)
            __hip_atomic_fetch_add(&buf[base + (size_t)di], v,
                                   __ATOMIC_RELAXED, __HIP_MEMORY_SCOPE_WORKGROUP);
        else
            atomicAdd(&buf[di], v);
    }
}

// out[i] += dinv[i] * sum_k buf[k][i]
template<int NC>
__global__ void finalize_kernel(const float* __restrict__ buf, const float* __restrict__ dinv,
                                float* __restrict__ out, int N) {
    int i = blockIdx.x * blockDim.x + threadIdx.x;
    if (i < N) {
        float a = 0.f;
#pragma unroll
        for (int k = 0; k < NC; ++k) a += buf[(size_t)k * N + i];
        out[i] += dinv[i] * a;
    }
}

extern "C" void kernel_launch(void* const* d_in, const int* in_sizes, int n_in,
                              void* d_out, int out_size, void* d_ws, size_t ws_size,
                              hipStream_t stream) {
    const float* x      = (const float*)d_in[0];
    const int*   ei     = (const int*)d_in[1];
    const float* W      = (const float*)d_in[2];
    const float* b_conv = (const float*)d_in[3];
    const float* W_fc   = (const float*)d_in[4];
    const float* b_fc   = (const float*)d_in[5];
    float* out = (float*)d_out;

    const int N = in_sizes[0] / DF;   // 100000
    const int E = in_sizes[1] / 2;    // 3200000
    const int* src = ei;              // edge_index[0]
    const int* dst = ei + E;          // edge_index[1]

    char* ws = (char*)d_ws;
    float* wvec  = (float*)ws;                 // 256 f32
    float* cterm = wvec + 256;                 // 1 f32 (padded to 512)
    float* dinv  = (float*)(ws + 512 * 4);     // N f32
    float* tval  = dinv + N;                   // N f32
    float* buf   = tval + N;                   // NC*N f32 (count, then reused for scatter acc)

    const size_t need_multi = ((size_t)512 + 2 * (size_t)N + (size_t)NXCD * N) * 4;
    const bool multi = ws_size >= need_multi;

    const int eblocks = (E + 255) / 256;
    const int nblocks4 = (N + 3) / 4;
    const int nblocks = (N + 255) / 256;

    if (multi) {
        hipMemsetAsync(buf, 0, (size_t)NXCD * N * sizeof(float), stream);
        prep_kernel<<<1, 256, 0, stream>>>(W, b_conv, W_fc, b_fc, wvec, cterm);
        count_kernel<true><<<eblocks, 256, 0, stream>>>(dst, buf, N, E);
        node_kernel<NXCD><<<nblocks4, 256, 0, stream>>>(x, buf, wvec, cterm, dinv, tval, out, N);
        hipMemsetAsync(buf, 0, (size_t)NXCD * N * sizeof(float), stream);
        scatter_kernel<true><<<eblocks, 256, 0, stream>>>(src, dst, tval, buf, N, E);
        finalize_kernel<NXCD><<<nblocks, 256, 0, stream>>>(buf, dinv, out, N);
    } else {
        hipMemsetAsync(buf, 0, (size_t)N * sizeof(float), stream);
        prep_kernel<<<1, 256, 0, stream>>>(W, b_conv, W_fc, b_fc, wvec, cterm);
        count_kernel<false><<<eblocks, 256, 0, stream>>>(dst, buf, N, E);
        node_kernel<1><<<nblocks4, 256, 0, stream>>>(x, buf, wvec, cterm, dinv, tval, out, N);
        hipMemsetAsync(buf, 0, (size_t)N * sizeof(float), stream);
        scatter_kernel<false><<<eblocks, 256, 0, stream>>>(src, dst, tval, buf, N, E);
        finalize_kernel<1><<<nblocks, 256, 0, stream>>>(buf, dinv, out, N);
    }
}

// Round 3
// 98.563 us; speedup vs baseline: 3.5834x; 3.5834x over previous
//
#include <hip/hip_runtime.h>

#define DF 256
#define HID 16
#define WGS 512        // edge-pass blocks (W)
#define PBITS 8        // partition = 256 nodes
#define PMAX 512       // max partitions supported by LDS arrays

// w[k] = sum_j W[k,j]*W_fc[j];  c = b_conv.W_fc + b_fc
__global__ void prep_kernel(const float* __restrict__ W, const float* __restrict__ b_conv,
                            const float* __restrict__ W_fc, const float* __restrict__ b_fc,
                            float* __restrict__ wvec, float* __restrict__ cterm) {
    int k = threadIdx.x;
    float acc = 0.f;
#pragma unroll
    for (int j = 0; j < HID; ++j) acc += W[k * HID + j] * W_fc[j];
    wvec[k] = acc;
    if (k == 0) {
        float c = 0.f;
#pragma unroll
        for (int j = 0; j < HID; ++j) c += b_conv[j] * W_fc[j];
        cterm[0] = c + b_fc[0];
    }
}

// K1: per-block histogram over dst partitions -> cnt[w][p]
__global__ void hist_kernel(const int* __restrict__ dst, unsigned* __restrict__ cnt,
                            int P, int E, int Epw) {
    __shared__ unsigned h[PMAX];
    for (int i = threadIdx.x; i < P; i += blockDim.x) h[i] = 0;
    __syncthreads();
    int w = blockIdx.x;
    int e0 = w * Epw, e1 = min(E, e0 + Epw);
    for (int e = e0 + threadIdx.x; e < e1; e += blockDim.x)
        atomicAdd(&h[((unsigned)dst[e]) >> PBITS], 1u);
    __syncthreads();
    for (int i = threadIdx.x; i < P; i += blockDim.x) cnt[(size_t)w * P + i] = h[i];
}

// K2: per-partition exclusive scan over w (in place); colTotal[p] = total
__global__ void colscan_kernel(unsigned* __restrict__ cnt, unsigned* __restrict__ colTotal, int P) {
    __shared__ unsigned s[WGS];
    int p = blockIdx.x, w = threadIdx.x;
    unsigned v = cnt[(size_t)w * P + p];
    s[w] = v;
    __syncthreads();
    for (int off = 1; off < WGS; off <<= 1) {
        unsigned t = (w >= off) ? s[w - off] : 0u;
        __syncthreads();
        s[w] += t;
        __syncthreads();
    }
    cnt[(size_t)w * P + p] = s[w] - v;          // exclusive prefix
    if (w == WGS - 1) colTotal[p] = s[w];       // inclusive total
}

// K3: exclusive scan over partitions
__global__ void partscan_kernel(const unsigned* __restrict__ colTotal,
                                unsigned* __restrict__ partStart, int P) {
    __shared__ unsigned s[PMAX];
    int t = threadIdx.x;
    unsigned v = (t < P) ? colTotal[t] : 0u;
    s[t] = v;
    __syncthreads();
    for (int off = 1; off < PMAX; off <<= 1) {
        unsigned x = (t >= off) ? s[t - off] : 0u;
        __syncthreads();
        s[t] += x;
        __syncthreads();
    }
    if (t < P) partStart[t] = s[t] - v;
}

// K4: scatter edges into partition-contiguous bins, packed (src<<8 | dstLocal)
__global__ void binscatter_kernel(const int* __restrict__ src, const int* __restrict__ dst,
                                  const unsigned* __restrict__ cnt, const unsigned* __restrict__ partStart,
                                  unsigned* __restrict__ bins, int P, int E, int Epw) {
    __shared__ unsigned cur[PMAX];
    int w = blockIdx.x;
    for (int i = threadIdx.x; i < P; i += blockDim.x)
        cur[i] = partStart[i] + cnt[(size_t)w * P + i];
    __syncthreads();
    int e0 = w * Epw, e1 = min(E, e0 + Epw);
    for (int e = e0 + threadIdx.x; e < e1; e += blockDim.x) {
        unsigned d = (unsigned)dst[e];
        unsigned slot = atomicAdd(&cur[d >> PBITS], 1u);   // LDS atomic
        bins[slot] = ((unsigned)src[e] << PBITS) | (d & 255u);
    }
}

// K5: s[i] = x[i] . w   (one wave per row, coalesced float4)
__global__ void sval_kernel(const float* __restrict__ x, const float* __restrict__ wvec,
                            float* __restrict__ sv, int N) {
    int lane = threadIdx.x & 63;
    int row = blockIdx.x * 4 + (threadIdx.x >> 6);
    if (row >= N) return;
    float4 wv = reinterpret_cast<const float4*>(wvec)[lane];
    float4 xv = reinterpret_cast<const float4*>(x + (size_t)row * DF)[lane];
    float acc = xv.x * wv.x + xv.y * wv.y + xv.z * wv.z + xv.w * wv.w;
#pragma unroll
    for (int off = 32; off > 0; off >>= 1) acc += __shfl_xor(acc, off, 64);
    if (lane == 0) sv[row] = acc;
}

// K6: per-partition degree count from bins; write dinv, tval = s*dinv, out init = s/deg + c
__global__ void degfin_kernel(const unsigned* __restrict__ bins, const unsigned* __restrict__ partStart,
                              const unsigned* __restrict__ colTotal, const float* __restrict__ sv,
                              const float* __restrict__ cterm, float* __restrict__ dinv,
                              float* __restrict__ tval, float* __restrict__ out, int N) {
    int p = blockIdx.x;
    __shared__ unsigned dc[256];
    if (threadIdx.x < 256) dc[threadIdx.x] = 0;
    __syncthreads();
    unsigned b0 = partStart[p], b1 = b0 + colTotal[p];
    for (unsigned e = b0 + threadIdx.x; e < b1; e += blockDim.x)
        atomicAdd(&dc[bins[e] & 255u], 1u);
    __syncthreads();
    if (threadIdx.x < 256) {
        int i = (p << PBITS) + threadIdx.x;
        if (i < N) {
            float deg = 1.0f + (float)dc[threadIdx.x];
            float di = rsqrtf(deg);
            float s = sv[i];
            dinv[i] = di;
            tval[i] = s * di;
            out[i] = s / deg + cterm[0];
        }
    }
}

// K7: per-partition value reduction in LDS; out += dinv * acc
__global__ void reduce_kernel(const unsigned* __restrict__ bins, const unsigned* __restrict__ partStart,
                              const unsigned* __restrict__ colTotal, const float* __restrict__ tval,
                              const float* __restrict__ dinv, float* __restrict__ out, int N) {
    int p = blockIdx.x;
    __shared__ float acc[256];
    if (threadIdx.x < 256) acc[threadIdx.x] = 0.f;
    __syncthreads();
    unsigned b0 = partStart[p], b1 = b0 + colTotal[p];
    for (unsigned e = b0 + threadIdx.x; e < b1; e += blockDim.x) {
        unsigned b = bins[e];
        atomicAdd(&acc[b & 255u], tval[b >> PBITS]);   // LDS f32 atomic
    }
    __syncthreads();
    if (threadIdx.x < 256) {
        int i = (p << PBITS) + threadIdx.x;
        if (i < N) out[i] += dinv[i] * acc[threadIdx.x];
    }
}

// ---------- fallback (small ws): known-good global-atomic path ----------
__global__ void fb_count(const int* __restrict__ dst, unsigned* __restrict__ cnt, int E) {
    int stride = gridDim.x * blockDim.x;
    for (int e = blockIdx.x * blockDim.x + threadIdx.x; e < E; e += stride)
        atomicAdd(&cnt[dst[e]], 1u);
}
__global__ void fb_node(const unsigned* __restrict__ cnt, const float* __restrict__ sv,
                        const float* __restrict__ cterm, float* __restrict__ dinv,
                        float* __restrict__ tval, float* __restrict__ out, int N) {
    int i = blockIdx.x * blockDim.x + threadIdx.x;
    if (i < N) {
        float deg = 1.0f + (float)cnt[i];
        float di = rsqrtf(deg);
        float s = sv[i];
        dinv[i] = di; tval[i] = s * di;
        out[i] = s / deg + cterm[0];
    }
}
__global__ void fb_scatter(const int* __restrict__ src, const int* __restrict__ dst,
                           const float* __restrict__ tval, const float* __restrict__ dinv,
                           float* __restrict__ out, int E) {
    int stride = gridDim.x * blockDim.x;
    for (int e = blockIdx.x * blockDim.x + threadIdx.x; e < E; e += stride) {
        int si = src[e], di = dst[e];
        atomicAdd(&out[di], tval[si] * dinv[di]);
    }
}

extern "C" void kernel_launch(void* const* d_in, const int* in_sizes, int n_in,
                              void* d_out, int out_size, void* d_ws, size_t ws_size,
                              hipStream_t stream) {
    const float* x      = (const float*)d_in[0];
    const int*   ei     = (const int*)d_in[1];
    const float* W      = (const float*)d_in[2];
    const float* b_conv = (const float*)d_in[3];
    const float* W_fc   = (const float*)d_in[4];
    const float* b_fc   = (const float*)d_in[5];
    float* out = (float*)d_out;

    const int N = in_sizes[0] / DF;   // 100000
    const int E = in_sizes[1] / 2;    // 3200000
    const int* src = ei;
    const int* dst = ei + E;

    const int P   = (N + 255) >> PBITS;         // 391
    const int Epw = (E + WGS - 1) / WGS;        // 6250

    char* ws = (char*)d_ws;
    float* wvec  = (float*)ws;                       // 256 f32
    float* cterm = wvec + 256;                       // [pad to 512 f32]
    float* sv    = (float*)(ws + 512 * 4);           // N
    float* dinv  = sv + N;                           // N
    float* tval  = dinv + N;                         // N
    unsigned* colTotal  = (unsigned*)(tval + N);     // P (pad 512)
    unsigned* partStart = colTotal + 512;            // P (pad 512)
    unsigned* cnt       = partStart + 512;           // WGS*P
    unsigned* bins      = cnt + (size_t)WGS * P;     // E

    const size_t need = 512u * 4 + (size_t)3 * N * 4 + 2 * 512 * 4
                      + (size_t)WGS * P * 4 + (size_t)E * 4;

    if (P <= PMAX && ws_size >= need) {
        prep_kernel<<<1, 256, 0, stream>>>(W, b_conv, W_fc, b_fc, wvec, cterm);
        hist_kernel<<<WGS, WGS, 0, stream>>>(dst, cnt, P, E, Epw);
        colscan_kernel<<<P, WGS, 0, stream>>>(cnt, colTotal, P);
        partscan_kernel<<<1, PMAX, 0, stream>>>(colTotal, partStart, P);
        binscatter_kernel<<<WGS, WGS, 0, stream>>>(src, dst, cnt, partStart, bins, P, E, Epw);
        sval_kernel<<<(N + 3) / 4, 256, 0, stream>>>(x, wvec, sv, N);
        degfin_kernel<<<P, WGS, 0, stream>>>(bins, partStart, colTotal, sv, cterm, dinv, tval, out, N);
        reduce_kernel<<<P, WGS, 0, stream>>>(bins, partStart, colTotal, tval, dinv, out, N);
    } else {
        unsigned* fcnt = (unsigned*)(tval + N);      // N u32
        hipMemsetAsync(fcnt, 0, (size_t)N * 4, stream);
        prep_kernel<<<1, 256, 0, stream>>>(W, b_conv, W_fc, b_fc, wvec, cterm);
        fb_count<<<2048, 256, 0, stream>>>(dst, fcnt, E);
        sval_kernel<<<(N + 3) / 4, 256, 0, stream>>>(x, wvec, sv, N);
        fb_node<<<(N + 255) / 256, 256, 0, stream>>>(fcnt, sv, cterm, dinv, tval, out, N);
        fb_scatter<<<2048, 256, 0, stream>>>(src, dst, tval, dinv, out, E);
    }
}

// Round 4
// 97.174 us; speedup vs baseline: 3.6346x; 1.0143x over previous
//
#include <hip/hip_runtime.h>

#define DF 256
#define HID 16
#define WB 512          // number of sort blocks / runs per partition
#define TPB 512         // threads per block for edge kernels
#define PMAX 512        // max partitions (nodes/256)

// K1: s[i] = x[i] . w, with w = W @ W_fc computed per block (16KB L2 reads)
__global__ void sval_kernel(const float* __restrict__ x, const float* __restrict__ Wm,
                            const float* __restrict__ W_fc, float* __restrict__ sv, int N) {
    __shared__ float wl[DF];
    int k = threadIdx.x;  // 256 threads
    float a = 0.f;
#pragma unroll
    for (int j = 0; j < HID; ++j) a += Wm[k * HID + j] * W_fc[j];
    wl[k] = a;
    __syncthreads();
    int lane = threadIdx.x & 63;
    int wid = threadIdx.x >> 6;  // 0..3
    float4 wv = reinterpret_cast<const float4*>(wl)[lane];
    for (int row = blockIdx.x * 4 + wid; row < N; row += gridDim.x * 4) {
        float4 xv = reinterpret_cast<const float4*>(x + (size_t)row * DF)[lane];
        float acc = xv.x * wv.x + xv.y * wv.y + xv.z * wv.z + xv.w * wv.w;
#pragma unroll
        for (int off = 32; off > 0; off >>= 1) acc += __shfl_xor(acc, off, 64);
        if (lane == 0) sv[row] = acc;
    }
}

// K2: block-local counting sort of an edge slice by dst partition.
// Output: sorted[w*Epw .. w*Epw+m) packed (src<<8|dstLocal), partition-sorted;
//         runStart[p*WB + w] = slice-local offset of partition p's run (rows 0..P).
__global__ void sort_kernel(const int* __restrict__ src, const int* __restrict__ dst,
                            unsigned* __restrict__ runStart, unsigned* __restrict__ sorted,
                            int P, int E, int Epw) {
    extern __shared__ unsigned smem[];
    unsigned* pack  = smem;               // Epw
    unsigned* sortl = pack + Epw;         // Epw (also scan scratch)
    unsigned* offs  = sortl + Epw;        // P+1
    unsigned* cur   = offs + P + 1;       // P (hist, then scatter cursor)
    unsigned short* keyp = (unsigned short*)(cur + P);  // Epw

    const int w = blockIdx.x;
    const int e0 = w * Epw;
    int m = E - e0; if (m > Epw) m = Epw; if (m < 0) m = 0;

    for (int i = threadIdx.x; i < P; i += blockDim.x) cur[i] = 0;
    __syncthreads();
    for (int i = threadIdx.x; i < m; i += blockDim.x) {
        unsigned s = (unsigned)src[e0 + i];
        unsigned d = (unsigned)dst[e0 + i];
        keyp[i] = (unsigned short)(d >> 8);
        pack[i] = (s << 8) | (d & 255u);
        atomicAdd(&cur[d >> 8], 1u);
    }
    __syncthreads();
    // exclusive scan of cur[0..P) using sortl as scratch (Epw >= TPB guaranteed by launcher)
    int t = threadIdx.x;
    unsigned v = (t < P) ? cur[t] : 0u;
    sortl[t] = v;
    __syncthreads();
    for (int off = 1; off < blockDim.x; off <<= 1) {
        unsigned u = (t >= off) ? sortl[t - off] : 0u;
        __syncthreads();
        sortl[t] += u;
        __syncthreads();
    }
    if (t < P) offs[t] = sortl[t] - v;
    if (t == 0) offs[P] = (unsigned)m;
    __syncthreads();
    for (int i = threadIdx.x; i < P; i += blockDim.x) cur[i] = offs[i];
    __syncthreads();
    // LDS scatter into sorted order
    for (int i = threadIdx.x; i < m; i += blockDim.x) {
        unsigned slot = atomicAdd(&cur[keyp[i]], 1u);
        sortl[slot] = pack[i];
    }
    __syncthreads();
    // coalesced write-out
    for (int i = threadIdx.x; i < m; i += blockDim.x) sorted[(size_t)e0 + i] = sortl[i];
    for (int p = threadIdx.x; p <= P; p += blockDim.x) runStart[(size_t)p * WB + w] = offs[p];
}

// K3: per-partition degree count from runs; dinv, tval = s*dinv, out = s/deg + c
__global__ void degfin_kernel(const unsigned* __restrict__ sorted, const unsigned* __restrict__ runStart,
                              const float* __restrict__ sv, const float* __restrict__ b_conv,
                              const float* __restrict__ W_fc, const float* __restrict__ b_fc,
                              float* __restrict__ dinv, float* __restrict__ tval,
                              float* __restrict__ out, int N, int Epw) {
    __shared__ unsigned dc[256];
    __shared__ float cterm_s;
    const int p = blockIdx.x;
    if (threadIdx.x < 256) dc[threadIdx.x] = 0u;
    if (threadIdx.x == 0) {
        float c = 0.f;
#pragma unroll
        for (int j = 0; j < HID; ++j) c += b_conv[j] * W_fc[j];
        cterm_s = c + b_fc[0];
    }
    __syncthreads();
    const int t = threadIdx.x;  // = w
    unsigned s0 = runStart[(size_t)p * WB + t];
    unsigned s1 = runStart[(size_t)(p + 1) * WB + t];
    const unsigned* base = sorted + (size_t)t * Epw;
    for (unsigned j = s0; j < s1; ++j) atomicAdd(&dc[base[j] & 255u], 1u);
    __syncthreads();
    if (threadIdx.x < 256) {
        int i = (p << 8) + threadIdx.x;
        if (i < N) {
            float deg = 1.0f + (float)dc[threadIdx.x];
            float di = rsqrtf(deg);
            float s = sv[i];
            dinv[i] = di;
            tval[i] = s * di;
            out[i] = s / deg + cterm_s;
        }
    }
}

// K4: per-partition value reduction; out += dinv * sum(tval[src])
__global__ void reduce_kernel(const unsigned* __restrict__ sorted, const unsigned* __restrict__ runStart,
                              const float* __restrict__ tval, const float* __restrict__ dinv,
                              float* __restrict__ out, int N, int Epw) {
    __shared__ float acc[256];
    const int p = blockIdx.x;
    if (threadIdx.x < 256) acc[threadIdx.x] = 0.f;
    __syncthreads();
    const int t = threadIdx.x;
    unsigned s0 = runStart[(size_t)p * WB + t];
    unsigned s1 = runStart[(size_t)(p + 1) * WB + t];
    const unsigned* base = sorted + (size_t)t * Epw;
    for (unsigned j = s0; j < s1; ++j) {
        unsigned v = base[j];
        atomicAdd(&acc[v & 255u], tval[v >> 8]);
    }
    __syncthreads();
    if (threadIdx.x < 256) {
        int i = (p << 8) + threadIdx.x;
        if (i < N) out[i] += dinv[i] * acc[threadIdx.x];
    }
}

// ---------- fallback: global-atomic path (known-good round-1 structure) ----------
__global__ void fb_count(const int* __restrict__ dst, unsigned* __restrict__ cnt, int E) {
    int stride = gridDim.x * blockDim.x;
    for (int e = blockIdx.x * blockDim.x + threadIdx.x; e < E; e += stride)
        atomicAdd(&cnt[dst[e]], 1u);
}
__global__ void fb_node(const unsigned* __restrict__ cnt, const float* __restrict__ sv,
                        const float* __restrict__ b_conv, const float* __restrict__ W_fc,
                        const float* __restrict__ b_fc, float* __restrict__ dinv,
                        float* __restrict__ tval, float* __restrict__ out, int N) {
    int i = blockIdx.x * blockDim.x + threadIdx.x;
    if (i < N) {
        float c = 0.f;
#pragma unroll
        for (int j = 0; j < HID; ++j) c += b_conv[j] * W_fc[j];
        float deg = 1.0f + (float)cnt[i];
        float di = rsqrtf(deg);
        float s = sv[i];
        dinv[i] = di; tval[i] = s * di;
        out[i] = s / deg + c + b_fc[0];
    }
}
__global__ void fb_scatter(const int* __restrict__ src, const int* __restrict__ dst,
                           const float* __restrict__ tval, const float* __restrict__ dinv,
                           float* __restrict__ out, int E) {
    int stride = gridDim.x * blockDim.x;
    for (int e = blockIdx.x * blockDim.x + threadIdx.x; e < E; e += stride) {
        int si = src[e], di = dst[e];
        atomicAdd(&out[di], tval[si] * dinv[di]);
    }
}

extern "C" void kernel_launch(void* const* d_in, const int* in_sizes, int n_in,
                              void* d_out, int out_size, void* d_ws, size_t ws_size,
                              hipStream_t stream) {
    const float* x      = (const float*)d_in[0];
    const int*   ei     = (const int*)d_in[1];
    const float* Wm     = (const float*)d_in[2];
    const float* b_conv = (const float*)d_in[3];
    const float* W_fc   = (const float*)d_in[4];
    const float* b_fc   = (const float*)d_in[5];
    float* out = (float*)d_out;

    const int N = in_sizes[0] / DF;   // 100000
    const int E = in_sizes[1] / 2;    // 3200000
    const int* src = ei;
    const int* dst = ei + E;

    const int P   = (N + 255) >> 8;           // 391
    const int Epw = (E + WB - 1) / WB;        // 6250

    char* ws = (char*)d_ws;
    float* sv   = (float*)ws;                        // N
    float* dinv = sv + N;                            // N
    float* tval = dinv + N;                          // N
    unsigned* runStart = (unsigned*)(tval + N);      // (P+1)*WB
    unsigned* sorted   = runStart + (size_t)(P + 1) * WB;  // WB*Epw

    const size_t need = ((size_t)3 * N + (size_t)(P + 1) * WB + (size_t)WB * Epw) * 4;
    const size_t shbytes = (size_t)Epw * 10 + (size_t)(2 * P + 2) * 4 + 64;

    if (P <= PMAX && Epw >= TPB && ws_size >= need && shbytes <= 160 * 1024) {
        sval_kernel<<<2048, 256, 0, stream>>>(x, Wm, W_fc, sv, N);
        sort_kernel<<<WB, TPB, shbytes, stream>>>(src, dst, runStart, sorted, P, E, Epw);
        degfin_kernel<<<P, TPB, 0, stream>>>(sorted, runStart, sv, b_conv, W_fc, b_fc,
                                             dinv, tval, out, N, Epw);
        reduce_kernel<<<P, TPB, 0, stream>>>(sorted, runStart, tval, dinv, out, N, Epw);
    } else {
        unsigned* fcnt = (unsigned*)(tval + N);      // N u32
        hipMemsetAsync(fcnt, 0, (size_t)N * 4, stream);
        sval_kernel<<<2048, 256, 0, stream>>>(x, Wm, W_fc, sv, N);
        fb_count<<<2048, 256, 0, stream>>>(dst, fcnt, E);
        fb_node<<<(N + 255) / 256, 256, 0, stream>>>(fcnt, sv, b_conv, W_fc, b_fc, dinv, tval, out, N);
        fb_scatter<<<2048, 256, 0, stream>>>(src, dst, tval, dinv, out, E);
    }
}